// Round 9
// baseline (417.461 us; speedup 1.0000x reference)
//
#include <hip/hip_runtime.h>

// ---------------- common ----------------
typedef float  f32x4   __attribute__((ext_vector_type(4)));
typedef short  bf16x8  __attribute__((ext_vector_type(8)));
typedef unsigned short u16;
typedef unsigned int   u32;

static __device__ __forceinline__ u16 f2bf(float f) {   // RNE float -> bf16
    u32 u = __float_as_uint(f);
    u += 0x7FFFu + ((u >> 16) & 1u);
    return (u16)(u >> 16);
}
static __device__ __forceinline__ f32x4 unpk(uint2 p) { // 4 packed bf16 -> f32x4
    f32x4 r;
    r[0] = __uint_as_float(p.x << 16);
    r[1] = __uint_as_float(p.x & 0xFFFF0000u);
    r[2] = __uint_as_float(p.y << 16);
    r[3] = __uint_as_float(p.y & 0xFFFF0000u);
    return r;
}

// dims: B=8 N=128 F_IN=64 F_E=16 H=256 L=8

// ---------------- setup kernels ----------------

// h0 = x @ node_W + node_b, then mask + layernorm(l=0) -> bf16.  grid: 1024 x 256
__global__ void k_h0ln(const float* __restrict__ x, const float* __restrict__ nW,
                       const float* __restrict__ nb, const int* __restrict__ mask,
                       const float* __restrict__ lng, const float* __restrict__ lnb,
                       float* __restrict__ h, u16* __restrict__ hnbf) {
    __shared__ float xr[64];
    __shared__ float rs[4], rs2[4];
    int row = blockIdx.x, c = threadIdx.x;
    if (c < 64) xr[c] = x[row * 64 + c];
    __syncthreads();
    float acc = nb[c];
#pragma unroll
    for (int k = 0; k < 64; ++k) acc += xr[k] * nW[k * 256 + c];
    float mv = (float)mask[row];
    float v = acc * mv;
    h[row * 256 + c] = v;
    float s = v, s2 = v * v;
    int w = c >> 6, lane = c & 63;
#pragma unroll
    for (int off = 32; off; off >>= 1) {
        s  += __shfl_xor(s,  off);
        s2 += __shfl_xor(s2, off);
    }
    if (lane == 0) { rs[w] = s; rs2[w] = s2; }
    __syncthreads();
    float S  = rs[0] + rs[1] + rs[2] + rs[3];
    float S2 = rs2[0] + rs2[1] + rs2[2] + rs2[3];
    float mu  = S * (1.f / 256.f);
    float var = S2 * (1.f / 256.f) - mu * mu;
    float rstd = rsqrtf(var + 1e-5f);
    hnbf[row * 256 + c] = f2bf((v - mu) * rstd * lng[c] + lnb[c]);
}

// edge_attr -> bf16 fragment layout (16x16x32 B), K padded 16->32 with zeros.
__global__ void k_edgefrag(const float* __restrict__ ea, u16* __restrict__ ef) {
    int gid = blockIdx.x * 256 + threadIdx.x;
    int lane = gid & 63, nt = (gid >> 6) & 7, i = (gid >> 9) & 127, b = gid >> 16;
    int j = nt * 16 + (lane & 15), k0 = (lane >> 4) * 8;
    uint4 out = {0u, 0u, 0u, 0u};
    if (k0 < 16) {
        const float* p = ea + (((size_t)(b * 128 + i) * 128 + j) * 16 + k0);
        u16 us[8];
#pragma unroll
        for (int t = 0; t < 8; ++t) us[t] = f2bf(p[t]);
        out.x = (u32)us[0] | ((u32)us[1] << 16);
        out.y = (u32)us[2] | ((u32)us[3] << 16);
        out.z = (u32)us[4] | ((u32)us[5] << 16);
        out.w = (u32)us[6] | ((u32)us[7] << 16);
    }
    ((uint4*)ef)[gid] = out;
}

// W1^T / W2^T fragment packs (16x16x32 A): wt[((l*8+kt)*16+mt)*64+lane][8]
__global__ void k_wt(const float* __restrict__ W1, const float* __restrict__ W2,
                     u16* __restrict__ w1t, u16* __restrict__ w2t) {
    int gid = blockIdx.x * 256 + threadIdx.x;
    int lane = gid & 63, mt = (gid >> 6) & 15, kt = (gid >> 10) & 7, l = gid >> 13;
    int hh = mt * 16 + (lane & 15), k = kt * 32 + (lane >> 4) * 8;
    u16 a[8], b[8];
#pragma unroll
    for (int t = 0; t < 8; ++t) {
        size_t idx = (size_t)l * 65536 + (size_t)(k + t) * 256 + hh;
        a[t] = f2bf(W1[idx]);
        b[t] = f2bf(W2[idx]);
    }
    uint4 oa, ob;
    oa.x = (u32)a[0] | ((u32)a[1] << 16); oa.y = (u32)a[2] | ((u32)a[3] << 16);
    oa.z = (u32)a[4] | ((u32)a[5] << 16); oa.w = (u32)a[6] | ((u32)a[7] << 16);
    ob.x = (u32)b[0] | ((u32)b[1] << 16); ob.y = (u32)b[2] | ((u32)b[3] << 16);
    ob.z = (u32)b[4] | ((u32)b[5] << 16); ob.w = (u32)b[6] | ((u32)b[7] << 16);
    ((uint4*)w1t)[gid] = oa;
    ((uint4*)w2t)[gid] = ob;
}

// ro_pW^T fragment pack (16x16x32 A): pwt[(kt*16+mt)*64+lane][8]
__global__ void k_pwt(const float* __restrict__ pW, u16* __restrict__ pwt) {
    int gid = blockIdx.x * 256 + threadIdx.x;
    int lane = gid & 63, mt = (gid >> 6) & 15, kt = gid >> 10;
    int hh = mt * 16 + (lane & 15), k = kt * 32 + (lane >> 4) * 8;
    u16 a[8];
#pragma unroll
    for (int t = 0; t < 8; ++t) a[t] = f2bf(pW[(size_t)(k + t) * 256 + hh]);
    uint4 o;
    o.x = (u32)a[0] | ((u32)a[1] << 16); o.y = (u32)a[2] | ((u32)a[3] << 16);
    o.z = (u32)a[4] | ((u32)a[5] << 16); o.w = (u32)a[6] | ((u32)a[7] << 16);
    ((uint4*)pwt)[gid] = o;
}

// Wf1 = edge_W @ W1[l] (A-fragment pack) AND bias1 = edge_b @ W1[l] + b1[l]
__global__ void k_wf1b(const float* __restrict__ eW, const float* __restrict__ eb,
                       const float* __restrict__ W1, const float* __restrict__ b1,
                       u16* __restrict__ wf, float* __restrict__ bias1) {
    __shared__ float eWsT[256 * 16];   // [c][k]
    __shared__ float ebS[256];
    int l = blockIdx.x, tid = threadIdx.x;
#pragma unroll
    for (int k = 0; k < 16; ++k) eWsT[tid * 16 + k] = eW[k * 256 + tid];
    ebS[tid] = eb[tid];
    __syncthreads();
    float acc[16];
#pragma unroll
    for (int k = 0; k < 16; ++k) acc[k] = 0.f;
    float bacc = b1[l * 256 + tid];
    const float* w1c = W1 + (size_t)l * 65536 + tid;
    for (int c = 0; c < 256; ++c) {
        float wv = w1c[(size_t)c * 256];
        const f32x4* e = (const f32x4*)&eWsT[c * 16];
#pragma unroll
        for (int q = 0; q < 4; ++q) {
            f32x4 ev = e[q];
#pragma unroll
            for (int t = 0; t < 4; ++t) acc[q * 4 + t] += ev[t] * wv;
        }
        bacc += ebS[c] * wv;
    }
    bias1[l * 256 + tid] = bacc;
    int mt = tid >> 4, lo = tid & 15;
#pragma unroll
    for (int c4 = 0; c4 < 4; ++c4) {
        u16 us[8];
#pragma unroll
        for (int t = 0; t < 8; ++t) {
            int k = c4 * 8 + t;
            us[t] = (k < 16) ? f2bf(acc[k]) : (u16)0;
        }
        uint4 o;
        o.x = (u32)us[0] | ((u32)us[1] << 16);
        o.y = (u32)us[2] | ((u32)us[3] << 16);
        o.z = (u32)us[4] | ((u32)us[5] << 16);
        o.w = (u32)us[6] | ((u32)us[7] << 16);
        ((uint4*)wf)[(size_t)(l * 16 + mt) * 64 + c4 * 16 + lo] = o;
    }
}

// ---------------- per-layer kernels ----------------

// hn1' = h_norm @ W1[l] + bias1[l], bf16-packed fragment-permuted output.
// hn1p[b][((mt*8+nt)*64+lane)*4 .. +3] = 4 bf16.   grid: 128 x 256
__global__ __launch_bounds__(256) void k_hn1(const u16* __restrict__ w1t,
        const u16* __restrict__ hnbf, const float* __restrict__ bias1,
        u16* __restrict__ hn1p, int l) {
    int orig = blockIdx.x;
    int bid = (orig & 7) * 16 + (orig >> 3);      // XCD swizzle
    int b = bid >> 4, mt = bid & 15;
    int tid = threadIdx.x, w = tid >> 6, lane = tid & 63;
    f32x4 bv = *(const f32x4*)(bias1 + l * 256 + mt * 16 + (lane >> 4) * 4);
    f32x4 acc0 = bv, acc1 = bv;
    int j0 = (w * 2) * 16 + (lane & 15), j1 = j0 + 16;
#pragma unroll
    for (int kt = 0; kt < 8; ++kt) {
        bf16x8 a = *(const bf16x8*)(w1t + ((size_t)((l * 8 + kt) * 16 + mt) * 64 + lane) * 8);
        bf16x8 bt0 = *(const bf16x8*)(hnbf + ((size_t)(b * 128 + j0) * 256 + kt * 32 + (lane >> 4) * 8));
        bf16x8 bt1 = *(const bf16x8*)(hnbf + ((size_t)(b * 128 + j1) * 256 + kt * 32 + (lane >> 4) * 8));
        acc0 = __builtin_amdgcn_mfma_f32_16x16x32_bf16(a, bt0, acc0, 0, 0, 0);
        acc1 = __builtin_amdgcn_mfma_f32_16x16x32_bf16(a, bt1, acc1, 0, 0, 0);
    }
    u16* outb = hn1p + (size_t)b * 32768;
    uint2 p0, p1;
    p0.x = (u32)f2bf(acc0[0]) | ((u32)f2bf(acc0[1]) << 16);
    p0.y = (u32)f2bf(acc0[2]) | ((u32)f2bf(acc0[3]) << 16);
    p1.x = (u32)f2bf(acc1[0]) | ((u32)f2bf(acc1[1]) << 16);
    p1.y = (u32)f2bf(acc1[2]) | ((u32)f2bf(acc1[3]) << 16);
    *(uint2*)(outb + ((size_t)(mt * 8 + w * 2) * 64 + lane) * 4)     = p0;
    *(uint2*)(outb + ((size_t)(mt * 8 + w * 2 + 1) * 64 + lane) * 4) = p1;
}

// money kernel: 2 nodes per block, shared a2/hn1p; rank-compacted t1S.
// grid: 512 x 512, 2 blocks/CU (one fully-resident round)
__global__ __launch_bounds__(512, 4) void k_msg(
        const u16* __restrict__ wf1t, const u16* __restrict__ ef,
        const u16* __restrict__ w2t,  const u16* __restrict__ hn1p,
        const float* __restrict__ b2, const int* __restrict__ adj,
        const int* __restrict__ mask, float* __restrict__ h,
        const float* __restrict__ lngN, const float* __restrict__ lnbN,
        u16* __restrict__ hnbf, int l, int doLN) {

    __shared__ __align__(16) u16  t1S[8 * 8 * 64 * 8];   // 64 KiB [kt][n][64][8]
    __shared__ __align__(16) float b2S[256];
    __shared__ __align__(16) float msgS[256];
    __shared__ int rankS[2][128];
    __shared__ int cntS[2];
    __shared__ float rs[8], rs2[8];

    int orig = blockIdx.x;
    int bid = (orig & 7) * 64 + (orig >> 3);      // XCD swizzle: b == XCD
    int b = bid >> 6, ip = bid & 63;
    int i0 = ip * 2;
    int tid = threadIdx.x, w = tid >> 6, lane = tid & 63;
    int row0 = b * 128 + i0;

    if (tid < 256) b2S[tid] = b2[l * 256 + tid];
    if (w < 2) {   // wave 0 ranks i0, wave 1 ranks i1
        int rr = row0 + w;
        int f0 = adj[(size_t)rr * 128 + lane] != 0;
        int f1 = adj[(size_t)rr * 128 + 64 + lane] != 0;
        unsigned long long m0 = __ballot(f0);
        unsigned long long m1 = __ballot(f1);
        unsigned long long lt = (1ull << lane) - 1ull;
        int c0 = __popcll(m0);
        rankS[w][lane]      = f0 ? __popcll(m0 & lt)      : -1;
        rankS[w][64 + lane] = f1 ? c0 + __popcll(m1 & lt) : -1;
        if (lane == 0) cntS[w] = c0 + __popcll(m1);
    }
    __syncthreads();

    int mt0 = w * 2, mt1 = w * 2 + 1;
    // persistent W2 fragments (shared across both nodes)
    bf16x8 a2[8][2];
#pragma unroll
    for (int kt = 0; kt < 8; ++kt) {
        a2[kt][0] = *(const bf16x8*)(w2t + ((size_t)((l * 8 + kt) * 16 + mt0) * 64 + lane) * 8);
        a2[kt][1] = *(const bf16x8*)(w2t + ((size_t)((l * 8 + kt) * 16 + mt1) * 64 + lane) * 8);
    }
    bf16x8 aG0 = *(const bf16x8*)(wf1t + ((size_t)(l * 16 + mt0) * 64 + lane) * 8);
    bf16x8 aG1 = *(const bf16x8*)(wf1t + ((size_t)(l * 16 + mt1) * 64 + lane) * 8);

    const u16* hpb = hn1p + (size_t)b * 32768;
    int g0   = (lane >> 5) * 16;
    int g1   = 32 + g0;
    int toff = ((lane >> 4) & 1) * 4;
    int hb0 = mt0 * 16 + (lane >> 4) * 4;
    int hb1 = mt1 * 16 + (lane >> 4) * 4;
    f32x4 bv0 = *(const f32x4*)(&b2S[hb0]);
    f32x4 bv1 = *(const f32x4*)(&b2S[hb1]);

    float vkeep = 0.f;   // residual value carried tailA -> tailB
    int rowc = row0;     // current row for tail phases

#define ZEROTAIL(CNT, NTv)                                                        \
    {   int c = (CNT) + (lane >> 2); int kg = lane & 3;                           \
        if (c < (NTv) * 16) {                                                     \
            uint4 z = {0u, 0u, 0u, 0u};                                           \
            *(uint4*)(t1S + ((size_t)((w * 8 + (c >> 4)) * 64 + kg * 16 + (c & 15)) * 8)) = z; } }

#define GEMM1(ROW, II)                                                            \
    {   const u16* efb = ef + (size_t)(ROW) * 4096;                               \
        _Pragma("unroll")                                                         \
        for (int nt = 0; nt < 8; ++nt) {                                          \
            bf16x8 be = *(const bf16x8*)(efb + (size_t)(nt * 64 + lane) * 8);     \
            int r = rankS[II][nt * 16 + (lane & 15)];                             \
            uint2 c0p = *(const uint2*)(hpb + ((size_t)(mt0 * 8 + nt) * 64 + lane) * 4); \
            f32x4 acc0 = __builtin_amdgcn_mfma_f32_16x16x32_bf16(aG0, be, unpk(c0p), 0, 0, 0); \
            uint2 c1p = *(const uint2*)(hpb + ((size_t)(mt1 * 8 + nt) * 64 + lane) * 4); \
            f32x4 acc1 = __builtin_amdgcn_mfma_f32_16x16x32_bf16(aG1, be, unpk(c1p), 0, 0, 0); \
            if (r >= 0) {                                                         \
                int base = (w * 8 + (r >> 4)) * 64 + (r & 15);                    \
                uint2 pk0, pk1;                                                   \
                pk0.x = (u32)f2bf(fmaxf(acc0[0], 0.f)) | ((u32)f2bf(fmaxf(acc0[1], 0.f)) << 16); \
                pk0.y = (u32)f2bf(fmaxf(acc0[2], 0.f)) | ((u32)f2bf(fmaxf(acc0[3], 0.f)) << 16); \
                pk1.x = (u32)f2bf(fmaxf(acc1[0], 0.f)) | ((u32)f2bf(fmaxf(acc1[1], 0.f)) << 16); \
                pk1.y = (u32)f2bf(fmaxf(acc1[2], 0.f)) | ((u32)f2bf(fmaxf(acc1[3], 0.f)) << 16); \
                *(uint2*)(t1S + ((size_t)(base + g0)) * 8 + toff) = pk0;          \
                *(uint2*)(t1S + ((size_t)(base + g1)) * 8 + toff) = pk1;          \
            } } }

#define GEMM2RED(CNT)                                                             \
    {   int NTv = ((CNT) + 15) >> 4;                                              \
        f32x4 ms0 = (f32x4){0.f, 0.f, 0.f, 0.f};                                  \
        f32x4 ms1 = (f32x4){0.f, 0.f, 0.f, 0.f};                                  \
        for (int n = 0; n < NTv; ++n) {                                           \
            f32x4 acc0 = (f32x4){0.f, 0.f, 0.f, 0.f};                             \
            f32x4 acc1 = (f32x4){0.f, 0.f, 0.f, 0.f};                             \
            _Pragma("unroll")                                                     \
            for (int kt = 0; kt < 8; ++kt) {                                      \
                bf16x8 bt = *(const bf16x8*)(t1S + ((size_t)(kt * 8 + n) * 64 + lane) * 8); \
                acc0 = __builtin_amdgcn_mfma_f32_16x16x32_bf16(a2[kt][0], bt, acc0, 0, 0, 0); \
                acc1 = __builtin_amdgcn_mfma_f32_16x16x32_bf16(a2[kt][1], bt, acc1, 0, 0, 0); \
            }                                                                     \
            bool ok = (n * 16 + (lane & 15)) < (CNT);                             \
            _Pragma("unroll")                                                     \
            for (int r = 0; r < 4; ++r) {                                         \
                ms0[r] += ok ? fmaxf(acc0[r] + bv0[r], 0.f) : 0.f;                \
                ms1[r] += ok ? fmaxf(acc1[r] + bv1[r], 0.f) : 0.f;                \
            } }                                                                   \
        _Pragma("unroll")                                                         \
        for (int r = 0; r < 4; ++r) {                                             \
            ms0[r] += __shfl_xor(ms0[r], 1); ms1[r] += __shfl_xor(ms1[r], 1);     \
            ms0[r] += __shfl_xor(ms0[r], 2); ms1[r] += __shfl_xor(ms1[r], 2);     \
            ms0[r] += __shfl_xor(ms0[r], 4); ms1[r] += __shfl_xor(ms1[r], 4);     \
            ms0[r] += __shfl_xor(ms0[r], 8); ms1[r] += __shfl_xor(ms1[r], 8);     \
        }                                                                         \
        if ((lane & 15) == 0) {                                                   \
            *(f32x4*)(&msgS[hb0]) = ms0;                                          \
            *(f32x4*)(&msgS[hb1]) = ms1;                                          \
        } }

#define TAIL_A(ROW)                                                               \
    {   vkeep = 0.f;                                                              \
        if (tid < 256) {                                                          \
            float mv = (float)mask[ROW];                                          \
            vkeep = (h[(size_t)(ROW) * 256 + tid] + msgS[tid]) * mv;              \
            h[(size_t)(ROW) * 256 + tid] = vkeep;                                 \
        }                                                                         \
        float s = vkeep, s2 = vkeep * vkeep;                                      \
        _Pragma("unroll")                                                         \
        for (int off = 32; off; off >>= 1) {                                      \
            s  += __shfl_xor(s,  off);                                            \
            s2 += __shfl_xor(s2, off);                                            \
        }                                                                         \
        if (lane == 0) { rs[w] = s; rs2[w] = s2; } }

#define TAIL_B(ROW)                                                               \
    if (tid < 256) {                                                              \
        float o;                                                                  \
        if (doLN) {                                                               \
            float S = 0.f, S2 = 0.f;                                              \
            _Pragma("unroll")                                                     \
            for (int t = 0; t < 8; ++t) { S += rs[t]; S2 += rs2[t]; }             \
            float mu  = S * (1.f / 256.f);                                        \
            float var = S2 * (1.f / 256.f) - mu * mu;                             \
            float rstd = rsqrtf(var + 1e-5f);                                     \
            o = (vkeep - mu) * rstd * lngN[tid] + lnbN[tid];                      \
        } else o = vkeep;                                                         \
        hnbf[(size_t)(ROW) * 256 + tid] = f2bf(o);                                \
    }

    int cnt0 = cntS[0], cnt1 = cntS[1];
    int NT0 = (cnt0 + 15) >> 4, NT1 = (cnt1 + 15) >> 4;

    // P1: node i0 GEMM1
    ZEROTAIL(cnt0, NT0);
    GEMM1(row0, 0);
    __syncthreads();
    // P2: node i0 GEMM2 + msg
    GEMM2RED(cnt0);
    __syncthreads();
    // P3: tailA(i0) || GEMM1(i1)
    rowc = row0;
    TAIL_A(rowc);
    ZEROTAIL(cnt1, NT1);
    GEMM1(row0 + 1, 1);
    __syncthreads();
    // P4: tailB(i0) || GEMM2(i1) + msg
    TAIL_B(rowc);
    GEMM2RED(cnt1);
    __syncthreads();
    // P5: tailA(i1)
    rowc = row0 + 1;
    TAIL_A(rowc);
    __syncthreads();
    // P6: tailB(i1)
    TAIL_B(rowc);

#undef ZEROTAIL
#undef GEMM1
#undef GEMM2RED
#undef TAIL_A
#undef TAIL_B
}

// ---------------- readout ----------------

// scores = tanh(h@pW+pb)@aW + ab via MFMA on raw bf16 h rows.  grid: 8 x 512
__global__ __launch_bounds__(512) void k_ro1(const u16* __restrict__ hbf,
        const u16* __restrict__ pwt, const float* __restrict__ pb,
        const float* __restrict__ aW, const float* __restrict__ ab,
        float* __restrict__ scores) {
    int b = blockIdx.x;
    int tid = threadIdx.x, w = tid >> 6, lane = tid & 63;
    f32x4 acc[16];
#pragma unroll
    for (int mt = 0; mt < 16; ++mt)
        acc[mt] = *(const f32x4*)(pb + mt * 16 + (lane >> 4) * 4);
#pragma unroll
    for (int kt = 0; kt < 8; ++kt) {
        bf16x8 bt = *(const bf16x8*)(hbf + ((size_t)(b * 128 + w * 16 + (lane & 15)) * 256 + kt * 32 + (lane >> 4) * 8));
#pragma unroll
        for (int mt = 0; mt < 16; ++mt) {
            bf16x8 a = *(const bf16x8*)(pwt + ((size_t)(kt * 16 + mt) * 64 + lane) * 8);
            acc[mt] = __builtin_amdgcn_mfma_f32_16x16x32_bf16(a, bt, acc[mt], 0, 0, 0);
        }
    }
    float sc = 0.f;
#pragma unroll
    for (int mt = 0; mt < 16; ++mt) {
#pragma unroll
        for (int r = 0; r < 4; ++r)
            sc += tanhf(acc[mt][r]) * aW[mt * 16 + (lane >> 4) * 4 + r];
    }
    sc += __shfl_xor(sc, 16);
    sc += __shfl_xor(sc, 32);
    if (lane < 16) scores[b * 128 + w * 16 + lane] = sc + ab[0];
}

__global__ void k_ro2(const float* __restrict__ h, const float* __restrict__ scores,
                      const int* __restrict__ mask, const float* __restrict__ phW,
                      const float* __restrict__ phb, float* __restrict__ out) {
    __shared__ float aS[128];
    __shared__ float rm[4], rc[4], red[4];
    int b = blockIdx.x, tid = threadIdx.x, w = tid >> 6, lane = tid & 63;
    float mv = 0.f, sv = -__builtin_inff();
    if (tid < 128) {
        mv = (float)mask[b * 128 + tid];
        if (mv > 0.f) sv = scores[b * 128 + tid];
    }
    float mx = sv, cs = mv;
#pragma unroll
    for (int off = 32; off; off >>= 1) {
        mx = fmaxf(mx, __shfl_xor(mx, off));
        cs += __shfl_xor(cs, off);
    }
    if (lane == 0) { rm[w] = mx; rc[w] = cs; }
    __syncthreads();
    mx = fmaxf(fmaxf(rm[0], rm[1]), fmaxf(rm[2], rm[3]));
    float cnt = rc[0] + rc[1] + rc[2] + rc[3];
    float e = (tid < 128 && mv > 0.f) ? expf(sv - mx) : 0.f;
    float se = e;
#pragma unroll
    for (int off = 32; off; off >>= 1) se += __shfl_xor(se, off);
    if (lane == 0) red[w] = se;
    __syncthreads();
    float S = red[0] + red[1] + red[2] + red[3];
    if (tid < 128) {
        float a;
        if (S > 0.f) a = e / S;
        else         a = (mv > 0.f) ? 1.f / fmaxf(cnt, 1.f) : 0.f;
        aS[tid] = a;
    }
    __syncthreads();
    float g = 0.f;
    const float* hb = h + (size_t)b * 128 * 256;
    for (int n = 0; n < 128; ++n) g += aS[n] * hb[(size_t)n * 256 + tid];
    float p = g * phW[tid];
#pragma unroll
    for (int off = 32; off; off >>= 1) p += __shfl_xor(p, off);
    __syncthreads();
    if (lane == 0) red[w] = p;
    __syncthreads();
    if (tid == 0) out[b] = red[0] + red[1] + red[2] + red[3] + phb[0];
}

// ---------------- host ----------------
extern "C" void kernel_launch(void* const* d_in, const int* in_sizes, int n_in,
                              void* d_out, int out_size, void* d_ws, size_t ws_size,
                              hipStream_t stream) {
    const float* x    = (const float*)d_in[0];
    const int*   adj  = (const int*)  d_in[1];
    const float* ea   = (const float*)d_in[2];
    const int*   mask = (const int*)  d_in[3];
    const float* nW   = (const float*)d_in[4];
    const float* nb   = (const float*)d_in[5];
    const float* eW   = (const float*)d_in[6];
    const float* eb   = (const float*)d_in[7];
    const float* lng  = (const float*)d_in[8];
    const float* lnb  = (const float*)d_in[9];
    const float* W1   = (const float*)d_in[10];
    const float* b1   = (const float*)d_in[11];
    const float* W2   = (const float*)d_in[12];
    const float* b2   = (const float*)d_in[13];
    const float* ropW = (const float*)d_in[14];
    const float* ropb = (const float*)d_in[15];
    const float* roaW = (const float*)d_in[16];
    const float* roab = (const float*)d_in[17];
    const float* phW  = (const float*)d_in[18];
    const float* phb  = (const float*)d_in[19];
    float* out = (float*)d_out;

    char* p = (char*)d_ws;
    auto alloc = [&](size_t bytes) { char* r = p; p += (bytes + 255) & ~(size_t)255; return r; };
    float* h     = (float*)alloc((size_t)8 * 128 * 256 * 4);
    u16*   hnbf  = (u16*)  alloc((size_t)8 * 128 * 256 * 2);
    u16*   hn1p  = (u16*)  alloc((size_t)8 * 32768 * 2);
    u16*   ef    = (u16*)  alloc((size_t)8 * 128 * 4096 * 2);
    u16*   wf1t  = (u16*)  alloc((size_t)8 * 16 * 64 * 8 * 2);
    u16*   w1t   = (u16*)  alloc((size_t)8 * 8 * 16 * 64 * 8 * 2);
    u16*   w2t   = (u16*)  alloc((size_t)8 * 8 * 16 * 64 * 8 * 2);
    u16*   pwt   = (u16*)  alloc((size_t)8 * 16 * 64 * 8 * 2);
    float* bias1 = (float*)alloc((size_t)8 * 256 * 4);
    float* scores= (float*)alloc((size_t)1024 * 4);

    k_h0ln    <<<1024, 256, 0, stream>>>(x, nW, nb, mask, lng, lnb, h, hnbf);
    k_edgefrag<<<2048, 256, 0, stream>>>(ea, ef);
    k_wt      <<<256,  256, 0, stream>>>(W1, W2, w1t, w2t);
    k_wf1b    <<<8,    256, 0, stream>>>(eW, eb, W1, b1, wf1t, bias1);
    k_pwt     <<<32,   256, 0, stream>>>(ropW, pwt);

    for (int l = 0; l < 8; ++l) {
        k_hn1<<<128,  256, 0, stream>>>(w1t, hnbf, bias1, hn1p, l);
        int doLN = (l < 7) ? 1 : 0;
        int ln_next = (l < 7) ? (l + 1) : l;
        k_msg<<<512, 512, 0, stream>>>(wf1t, ef, w2t, hn1p, b2, adj, mask, h,
                                       lng + ln_next * 256, lnb + ln_next * 256,
                                       hnbf, l, doLN);
    }

    k_ro1<<<8,   512, 0, stream>>>(hnbf, pwt, ropb, roaW, roab, scores);
    k_ro2<<<8,   256, 0, stream>>>(h, scores, mask, phW, phb, out);
}